// Round 1
// baseline (904.553 us; speedup 1.0000x reference)
//
#include <hip/hip_runtime.h>
#include <hip/hip_bf16.h>
#include <math.h>

#define F_IN 300
#define HDIM 128
#define HO   256   // combined Wl|Wr output dim
#define CLS  2
#define TM   16    // nodes per proj block
#define NPB  64    // nodes per hpool block

// Build Wt[k][t] = (t<128 ? Wl[t][k] : Wr[t-128][k])  -> k-major for coalesced reads
__global__ __launch_bounds__(256) void prepw_kernel(const float* __restrict__ Wl,
                                                    const float* __restrict__ Wr,
                                                    float* __restrict__ Wt) {
    int k = blockIdx.x;
    int t = threadIdx.x;
    float v = (t < HDIM) ? Wl[t * F_IN + k] : Wr[(t - HDIM) * F_IN + k];
    Wt[k * HO + t] = v;
}

// xP[n][0:128] = x[n] @ Wl.T ; xP[n][128:256] = x[n] @ Wr.T
__global__ __launch_bounds__(256) void proj_kernel(const float* __restrict__ x,
                                                   const float* __restrict__ Wt,
                                                   float* __restrict__ xP, int N) {
    __shared__ float xs[TM * F_IN];  // 19.2 KB
    int n0 = blockIdx.x * TM;
    int tid = threadIdx.x;
    int rows = N - n0; if (rows > TM) rows = TM;
    const float* xbase = x + (size_t)n0 * F_IN;
    int tot = rows * F_IN;
    for (int idx = tid; idx < tot; idx += 256) xs[idx] = xbase[idx];
    __syncthreads();

    float acc[TM];
#pragma unroll
    for (int m = 0; m < TM; ++m) acc[m] = 0.f;

    for (int k = 0; k < F_IN; k += 4) {
        float w0 = Wt[(k + 0) * HO + tid];
        float w1 = Wt[(k + 1) * HO + tid];
        float w2 = Wt[(k + 2) * HO + tid];
        float w3 = Wt[(k + 3) * HO + tid];
#pragma unroll
        for (int m = 0; m < TM; ++m) {
            // byte offset m*1200 + 4k, both multiples of 16 -> aligned ds_read_b128
            float4 xv = *reinterpret_cast<const float4*>(&xs[m * F_IN + k]);
            float a = acc[m];
            a = fmaf(xv.x, w0, a);
            a = fmaf(xv.y, w1, a);
            a = fmaf(xv.z, w2, a);
            a = fmaf(xv.w, w3, a);
            acc[m] = a;
        }
    }
#pragma unroll
    for (int m = 0; m < TM; ++m) {
        if (m < rows) xP[((size_t)(n0 + m)) * HO + tid] = acc[m];
    }
}

// msgH[dst] += xP[src][0:128]; deg[dst] += 1
__global__ __launch_bounds__(256) void scatter_kernel(const float* __restrict__ xP,
                                                      const int* __restrict__ ei,
                                                      float* __restrict__ msgH,
                                                      float* __restrict__ deg, int E) {
    int tid = blockIdx.x * 256 + threadIdx.x;
    int e = tid >> 5;
    if (e >= E) return;
    int j = tid & 31;
    int s = ei[e];       // src row
    int d = ei[E + e];   // dst row
    float4 v = *reinterpret_cast<const float4*>(&xP[(size_t)s * HO + j * 4]);
    float* o = &msgH[(size_t)d * HDIM + j * 4];
    atomicAdd(o + 0, v.x);
    atomicAdd(o + 1, v.y);
    atomicAdd(o + 2, v.z);
    atomicAdd(o + 3, v.w);
    if (j == 0) atomicAdd(&deg[d], 1.0f);
}

// h[n] = relu(msgH[n]/max(deg,1) + bl + xWr[n]); gpool[batch[n]] = max(...)
// batch is sorted -> keep running max in registers, flush on graph change.
__global__ __launch_bounds__(128) void hpool_kernel(const float* __restrict__ xP,
                                                    const float* __restrict__ msgH,
                                                    const float* __restrict__ deg,
                                                    const float* __restrict__ bl,
                                                    const int* __restrict__ batch,
                                                    float* __restrict__ gpool, int N) {
    int t = threadIdx.x;
    int n0 = blockIdx.x * NPB;
    if (n0 >= N) return;
    float blv = bl[t];
    float runmax = 0.f;
    int curg = batch[n0];
    int nmax = N - n0; if (nmax > NPB) nmax = NPB;
    for (int i = 0; i < nmax; ++i) {
        int n = n0 + i;
        int gb = batch[n];
        if (gb != curg) {
            atomicMax((unsigned int*)&gpool[curg * HDIM + t], __float_as_uint(runmax));
            runmax = 0.f;
            curg = gb;
        }
        float dg = deg[n];
        float rv = 1.0f / fmaxf(dg, 1.0f);
        float h = fmaf(msgH[(size_t)n * HDIM + t], rv, blv + xP[(size_t)n * HO + HDIM + t]);
        h = fmaxf(h, 0.f);
        runmax = fmaxf(runmax, h);
    }
    atomicMax((unsigned int*)&gpool[curg * HDIM + t], __float_as_uint(runmax));
}

__global__ __launch_bounds__(256) void root_kernel(const int* __restrict__ batch,
                                                   int* __restrict__ root, int N) {
    int i = blockIdx.x * 256 + threadIdx.x;
    if (i >= N) return;
    if (i == 0 || batch[i] != batch[i - 1]) root[batch[i]] = i;
}

// Per graph g: news = relu(x[root] @ W0.T + b0); h1 = relu([news|gpool] @ W1.T + b1);
// out = log_softmax(h1 @ W2.T + b2)
__global__ __launch_bounds__(128) void final_kernel(const float* __restrict__ x,
                                                    const int* __restrict__ root,
                                                    const float* __restrict__ gpool,
                                                    const float* __restrict__ W0,
                                                    const float* __restrict__ b0,
                                                    const float* __restrict__ W1,
                                                    const float* __restrict__ b1,
                                                    const float* __restrict__ W2,
                                                    const float* __restrict__ b2,
                                                    float* __restrict__ out) {
    __shared__ float xrow[F_IN];
    __shared__ float cat[HO];
    __shared__ float h1s[HDIM];
    __shared__ float part[2][2];
    int g = blockIdx.x, t = threadIdx.x;
    int r = root[g];
    const float* xr = x + (size_t)r * F_IN;
    for (int k = t; k < F_IN; k += HDIM) xrow[k] = xr[k];
    __syncthreads();

    float a = b0[t];
    const float* w0r = W0 + t * F_IN;
    for (int k = 0; k < F_IN; ++k) a = fmaf(xrow[k], w0r[k], a);
    cat[t] = fmaxf(a, 0.f);
    cat[HDIM + t] = gpool[g * HDIM + t];
    __syncthreads();

    float s = b1[t];
    const float* w1r = W1 + t * HO;
    for (int k = 0; k < HO; ++k) s = fmaf(cat[k], w1r[k], s);
    h1s[t] = fmaxf(s, 0.f);
    __syncthreads();

    float hv = h1s[t];
    float p0 = hv * W2[t];
    float p1 = hv * W2[HDIM + t];
#pragma unroll
    for (int o2 = 32; o2 > 0; o2 >>= 1) {
        p0 += __shfl_down(p0, o2);
        p1 += __shfl_down(p1, o2);
    }
    int lane = t & 63, wv = t >> 6;
    if (lane == 0) { part[0][wv] = p0; part[1][wv] = p1; }
    __syncthreads();
    if (t == 0) {
        float z0 = part[0][0] + part[0][1] + b2[0];
        float z1 = part[1][0] + part[1][1] + b2[1];
        float m = fmaxf(z0, z1);
        float lse = m + logf(expf(z0 - m) + expf(z1 - m));
        out[g * CLS + 0] = z0 - lse;
        out[g * CLS + 1] = z1 - lse;
    }
}

extern "C" void kernel_launch(void* const* d_in, const int* in_sizes, int n_in,
                              void* d_out, int out_size, void* d_ws, size_t ws_size,
                              hipStream_t stream) {
    const float* x     = (const float*)d_in[0];
    const int*   ei    = (const int*)d_in[1];
    const int*   batch = (const int*)d_in[2];
    const float* Wl    = (const float*)d_in[3];
    const float* bl    = (const float*)d_in[4];
    const float* Wr    = (const float*)d_in[5];
    const float* W0    = (const float*)d_in[6];
    const float* b0    = (const float*)d_in[7];
    const float* W1    = (const float*)d_in[8];
    const float* b1    = (const float*)d_in[9];
    const float* W2    = (const float*)d_in[10];
    const float* b2    = (const float*)d_in[11];
    float* out = (float*)d_out;

    int N = in_sizes[2];
    int E = in_sizes[1] / 2;
    int G = out_size / CLS;

    char* ws = (char*)d_ws;
    size_t off = 0;
    auto carve = [&](size_t bytes) -> void* {
        void* p = ws + off;
        off += (bytes + 255) & ~(size_t)255;
        return p;
    };
    float* xP    = (float*)carve((size_t)N * HO * sizeof(float));
    char*  zbeg  = ws + off;
    float* msgH  = (float*)carve((size_t)N * HDIM * sizeof(float));
    float* deg   = (float*)carve((size_t)N * sizeof(float));
    float* gpool = (float*)carve((size_t)G * HDIM * sizeof(float));
    char*  zend  = ws + off;
    float* Wt    = (float*)carve((size_t)F_IN * HO * sizeof(float));
    int*   root  = (int*)carve((size_t)G * sizeof(int));
    (void)ws_size; (void)n_in;

    // zero accumulators (must happen every call: harness does not re-poison)
    hipMemsetAsync(zbeg, 0, (size_t)(zend - zbeg), stream);

    prepw_kernel<<<F_IN, 256, 0, stream>>>(Wl, Wr, Wt);
    proj_kernel<<<(N + TM - 1) / TM, 256, 0, stream>>>(x, Wt, xP, N);
    scatter_kernel<<<(int)(((size_t)E * 32 + 255) / 256), 256, 0, stream>>>(xP, ei, msgH, deg, E);
    hpool_kernel<<<(N + NPB - 1) / NPB, HDIM, 0, stream>>>(xP, msgH, deg, bl, batch, gpool, N);
    root_kernel<<<(N + 255) / 256, 256, 0, stream>>>(batch, root, N);
    final_kernel<<<G, HDIM, 0, stream>>>(x, root, gpool, W0, b0, W1, b1, W2, b2, out);
}

// Round 2
// 524.270 us; speedup vs baseline: 1.7254x; 1.7254x over previous
//
#include <hip/hip_runtime.h>
#include <hip/hip_bf16.h>
#include <math.h>

#define F_IN 300
#define HDIM 128
#define HO   256   // combined Wl|Wr output dim
#define CLS  2
#define TM   16    // nodes per proj block
#define NPB  64    // nodes per gather/pool block
#define CHUNK 1024 // scan chunk (256 threads x 4)

// Build Wt[k][t] = (t<128 ? Wl[t][k] : Wr[t-128][k])  -> k-major for coalesced reads
__global__ __launch_bounds__(256) void prepw_kernel(const float* __restrict__ Wl,
                                                    const float* __restrict__ Wr,
                                                    float* __restrict__ Wt) {
    int k = blockIdx.x;
    int t = threadIdx.x;
    float v = (t < HDIM) ? Wl[t * F_IN + k] : Wr[(t - HDIM) * F_IN + k];
    Wt[k * HO + t] = v;
}

// xP[n][0:128] = x[n] @ Wl.T ; xP[n][128:256] = x[n] @ Wr.T
__global__ __launch_bounds__(256) void proj_kernel(const float* __restrict__ x,
                                                   const float* __restrict__ Wt,
                                                   float* __restrict__ xP, int N) {
    __shared__ float xs[TM * F_IN];  // 19.2 KB
    int n0 = blockIdx.x * TM;
    int tid = threadIdx.x;
    int rows = N - n0; if (rows > TM) rows = TM;
    const float* xbase = x + (size_t)n0 * F_IN;
    int tot = rows * F_IN;
    for (int idx = tid; idx < tot; idx += 256) xs[idx] = xbase[idx];
    __syncthreads();

    float acc[TM];
#pragma unroll
    for (int m = 0; m < TM; ++m) acc[m] = 0.f;

    for (int k = 0; k < F_IN; k += 4) {
        float w0 = Wt[(k + 0) * HO + tid];
        float w1 = Wt[(k + 1) * HO + tid];
        float w2 = Wt[(k + 2) * HO + tid];
        float w3 = Wt[(k + 3) * HO + tid];
#pragma unroll
        for (int m = 0; m < TM; ++m) {
            float4 xv = *reinterpret_cast<const float4*>(&xs[m * F_IN + k]);
            float a = acc[m];
            a = fmaf(xv.x, w0, a);
            a = fmaf(xv.y, w1, a);
            a = fmaf(xv.z, w2, a);
            a = fmaf(xv.w, w3, a);
            acc[m] = a;
        }
    }
#pragma unroll
    for (int m = 0; m < TM; ++m) {
        if (m < rows) xP[((size_t)(n0 + m)) * HO + tid] = acc[m];
    }
}

// ---- CSR build ----
__global__ __launch_bounds__(256) void count_kernel(const int* __restrict__ ei,
                                                    int* __restrict__ cnt, int E) {
    int e = blockIdx.x * 256 + threadIdx.x;
    if (e >= E) return;
    atomicAdd(&cnt[ei[E + e]], 1);   // dst
}

// exclusive scan, stage 1: per-chunk scan + chunk totals
__global__ __launch_bounds__(256) void scan1_kernel(const int* __restrict__ cnt,
                                                    int* __restrict__ tmp,
                                                    int* __restrict__ bsum, int N) {
    __shared__ int ssum[256];
    int t = threadIdx.x;
    int base = blockIdx.x * CHUNK + t * 4;
    int c[4];
#pragma unroll
    for (int j = 0; j < 4; ++j) c[j] = (base + j < N) ? cnt[base + j] : 0;
    int s = c[0] + c[1] + c[2] + c[3];
    ssum[t] = s;
    __syncthreads();
    for (int off = 1; off < 256; off <<= 1) {
        int a = (t >= off) ? ssum[t - off] : 0;
        __syncthreads();
        ssum[t] += a;
        __syncthreads();
    }
    int run = ssum[t] - s;  // exclusive prefix for this thread within chunk
#pragma unroll
    for (int j = 0; j < 4; ++j) {
        if (base + j < N) tmp[base + j] = run;
        run += c[j];
    }
    if (t == 255) bsum[blockIdx.x] = ssum[255];
}

// stage 2: exclusive scan of chunk totals (nb <= 256)
__global__ __launch_bounds__(256) void scan2_kernel(int* __restrict__ bsum, int nb) {
    __shared__ int sd[256];
    int t = threadIdx.x;
    int v = (t < nb) ? bsum[t] : 0;
    sd[t] = v;
    __syncthreads();
    for (int off = 1; off < 256; off <<= 1) {
        int a = (t >= off) ? sd[t - off] : 0;
        __syncthreads();
        sd[t] += a;
        __syncthreads();
    }
    if (t < nb) bsum[t] = sd[t] - v;  // exclusive
}

// stage 3: rowptr = tmp + bsum[chunk]; cursor starts equal to rowptr
__global__ __launch_bounds__(256) void scan3_kernel(const int* __restrict__ tmp,
                                                    const int* __restrict__ bsum,
                                                    int* __restrict__ rowptr,
                                                    int* __restrict__ cursor, int N) {
    int i = blockIdx.x * 256 + threadIdx.x;
    if (i >= N) return;
    int v = tmp[i] + bsum[i >> 10];
    rowptr[i] = v;
    cursor[i] = v;
}

// fill src lists; after this, cursor[n] == rowptr[n+1]
__global__ __launch_bounds__(256) void fill_kernel(const int* __restrict__ ei,
                                                   int* __restrict__ cursor,
                                                   int* __restrict__ srcl, int E) {
    int e = blockIdx.x * 256 + threadIdx.x;
    if (e >= E) return;
    int s = ei[e];
    int d = ei[E + e];
    int pos = atomicAdd(&cursor[d], 1);
    srcl[pos] = s;
}

// gather neighbors + h = relu(mean + bl + xWr) + global_max_pool (batch sorted)
__global__ __launch_bounds__(128) void gather_pool_kernel(const float* __restrict__ xP,
                                                          const int* __restrict__ rowptr,
                                                          const int* __restrict__ rowend,
                                                          const int* __restrict__ srcl,
                                                          const float* __restrict__ bl,
                                                          const int* __restrict__ batch,
                                                          float* __restrict__ gpool, int N) {
    int t = threadIdx.x;
    int n0 = blockIdx.x * NPB;
    if (n0 >= N) return;
    float blv = bl[t];
    float runmax = 0.f;
    int curg = batch[n0];
    int nmax = N - n0; if (nmax > NPB) nmax = NPB;
    for (int i = 0; i < nmax; ++i) {
        int n = n0 + i;
        int gb = batch[n];
        if (gb != curg) {
            atomicMax((unsigned int*)&gpool[curg * HDIM + t], __float_as_uint(runmax));
            runmax = 0.f;
            curg = gb;
        }
        int e0 = rowptr[n];
        int e1 = rowend[n];   // cursor after fill == rowptr[n+1]
        float acc = 0.f;
        for (int e = e0; e < e1; ++e) {
            int s = srcl[e];
            acc += xP[(size_t)s * HO + t];
        }
        float rv = 1.0f / fmaxf((float)(e1 - e0), 1.0f);
        float h = fmaf(acc, rv, blv + xP[(size_t)n * HO + HDIM + t]);
        h = fmaxf(h, 0.f);
        runmax = fmaxf(runmax, h);
    }
    atomicMax((unsigned int*)&gpool[curg * HDIM + t], __float_as_uint(runmax));
}

__global__ __launch_bounds__(256) void root_kernel(const int* __restrict__ batch,
                                                   int* __restrict__ root, int N) {
    int i = blockIdx.x * 256 + threadIdx.x;
    if (i >= N) return;
    if (i == 0 || batch[i] != batch[i - 1]) root[batch[i]] = i;
}

// Per graph g: news = relu(x[root] @ W0.T + b0); h1 = relu([news|gpool] @ W1.T + b1);
// out = log_softmax(h1 @ W2.T + b2)
__global__ __launch_bounds__(128) void final_kernel(const float* __restrict__ x,
                                                    const int* __restrict__ root,
                                                    const float* __restrict__ gpool,
                                                    const float* __restrict__ W0,
                                                    const float* __restrict__ b0,
                                                    const float* __restrict__ W1,
                                                    const float* __restrict__ b1,
                                                    const float* __restrict__ W2,
                                                    const float* __restrict__ b2,
                                                    float* __restrict__ out) {
    __shared__ float xrow[F_IN];
    __shared__ float cat[HO];
    __shared__ float h1s[HDIM];
    __shared__ float part[2][2];
    int g = blockIdx.x, t = threadIdx.x;
    int r = root[g];
    const float* xr = x + (size_t)r * F_IN;
    for (int k = t; k < F_IN; k += HDIM) xrow[k] = xr[k];
    __syncthreads();

    float a = b0[t];
    const float* w0r = W0 + t * F_IN;
    for (int k = 0; k < F_IN; ++k) a = fmaf(xrow[k], w0r[k], a);
    cat[t] = fmaxf(a, 0.f);
    cat[HDIM + t] = gpool[g * HDIM + t];
    __syncthreads();

    float s = b1[t];
    const float* w1r = W1 + t * HO;
    for (int k = 0; k < HO; ++k) s = fmaf(cat[k], w1r[k], s);
    h1s[t] = fmaxf(s, 0.f);
    __syncthreads();

    float hv = h1s[t];
    float p0 = hv * W2[t];
    float p1 = hv * W2[HDIM + t];
#pragma unroll
    for (int o2 = 32; o2 > 0; o2 >>= 1) {
        p0 += __shfl_down(p0, o2);
        p1 += __shfl_down(p1, o2);
    }
    int lane = t & 63, wv = t >> 6;
    if (lane == 0) { part[0][wv] = p0; part[1][wv] = p1; }
    __syncthreads();
    if (t == 0) {
        float z0 = part[0][0] + part[0][1] + b2[0];
        float z1 = part[1][0] + part[1][1] + b2[1];
        float m = fmaxf(z0, z1);
        float lse = m + logf(expf(z0 - m) + expf(z1 - m));
        out[g * CLS + 0] = z0 - lse;
        out[g * CLS + 1] = z1 - lse;
    }
}

extern "C" void kernel_launch(void* const* d_in, const int* in_sizes, int n_in,
                              void* d_out, int out_size, void* d_ws, size_t ws_size,
                              hipStream_t stream) {
    const float* x     = (const float*)d_in[0];
    const int*   ei    = (const int*)d_in[1];
    const int*   batch = (const int*)d_in[2];
    const float* Wl    = (const float*)d_in[3];
    const float* bl    = (const float*)d_in[4];
    const float* Wr    = (const float*)d_in[5];
    const float* W0    = (const float*)d_in[6];
    const float* b0    = (const float*)d_in[7];
    const float* W1    = (const float*)d_in[8];
    const float* b1    = (const float*)d_in[9];
    const float* W2    = (const float*)d_in[10];
    const float* b2    = (const float*)d_in[11];
    float* out = (float*)d_out;

    int N = in_sizes[2];
    int E = in_sizes[1] / 2;
    int G = out_size / CLS;

    char* ws = (char*)d_ws;
    size_t off = 0;
    auto carve = [&](size_t bytes) -> void* {
        void* p = ws + off;
        off += (bytes + 255) & ~(size_t)255;
        return p;
    };
    float* xP     = (float*)carve((size_t)N * HO * sizeof(float));
    char*  zbeg   = ws + off;
    int*   cnt    = (int*)carve((size_t)N * sizeof(int));
    float* gpool  = (float*)carve((size_t)G * HDIM * sizeof(float));
    char*  zend   = ws + off;
    int*   tmp    = (int*)carve((size_t)N * sizeof(int));
    int*   rowptr = (int*)carve((size_t)N * sizeof(int));
    int*   cursor = (int*)carve((size_t)N * sizeof(int));
    int*   srcl   = (int*)carve((size_t)E * sizeof(int));
    int*   bsum   = (int*)carve(1024 * sizeof(int));
    float* Wt     = (float*)carve((size_t)F_IN * HO * sizeof(float));
    int*   root   = (int*)carve((size_t)G * sizeof(int));
    (void)ws_size; (void)n_in;

    int nb = (N + CHUNK - 1) / CHUNK;   // scan chunks (130000 -> 127, fits one block)

    // zero accumulators (must happen every call: harness does not re-poison)
    hipMemsetAsync(zbeg, 0, (size_t)(zend - zbeg), stream);

    prepw_kernel<<<F_IN, 256, 0, stream>>>(Wl, Wr, Wt);
    proj_kernel<<<(N + TM - 1) / TM, 256, 0, stream>>>(x, Wt, xP, N);

    count_kernel<<<(E + 255) / 256, 256, 0, stream>>>(ei, cnt, E);
    scan1_kernel<<<nb, 256, 0, stream>>>(cnt, tmp, bsum, N);
    scan2_kernel<<<1, 256, 0, stream>>>(bsum, nb);
    scan3_kernel<<<(N + 255) / 256, 256, 0, stream>>>(tmp, bsum, rowptr, cursor, N);
    fill_kernel<<<(E + 255) / 256, 256, 0, stream>>>(ei, cursor, srcl, E);

    gather_pool_kernel<<<(N + NPB - 1) / NPB, HDIM, 0, stream>>>(xP, rowptr, cursor, srcl,
                                                                 bl, batch, gpool, N);
    root_kernel<<<(N + 255) / 256, 256, 0, stream>>>(batch, root, N);
    final_kernel<<<G, HDIM, 0, stream>>>(x, root, gpool, W0, b0, W1, b1, W2, b2, out);
}

// Round 3
// 292.086 us; speedup vs baseline: 3.0969x; 1.7949x over previous
//
#include <hip/hip_runtime.h>
#include <hip/hip_bf16.h>
#include <math.h>

#define F_IN 300
#define HDIM 128
#define HO   256   // combined Wl|Wr output dim
#define KP   320   // K padded to 10 x 32
#define NKS  10
#define CLS  2
#define MB   64    // node rows per proj block
#define NPB  64    // nodes per gather/pool block
#define CHUNK 1024 // scan chunk (256 threads x 4)

typedef short short8 __attribute__((ext_vector_type(8)));
typedef float f32x4 __attribute__((ext_vector_type(4)));

static __device__ __forceinline__ unsigned short f2bf(float f) {
    union { float f; unsigned int u; } v; v.f = f;
    unsigned int u = v.u;
    unsigned int r = (u + 0x7FFFu + ((u >> 16) & 1u)) >> 16;   // RNE
    return (unsigned short)r;
}
static __device__ __forceinline__ float bf2f(unsigned short h) {
    union { unsigned int u; float f; } v; v.u = ((unsigned int)h) << 16;
    return v.f;
}

// Pack W fragments: Wb[((ks*16+ct)*4+hi)*16+c15][j] bf16, k=ks*32+hi*8+j, c=ct*16+c15
// val = (c<128 ? Wl[c][k] : Wr[c-128][k]), 0 for k>=300.
__global__ __launch_bounds__(256) void prepw_kernel(const float* __restrict__ Wl,
                                                    const float* __restrict__ Wr,
                                                    unsigned short* __restrict__ Wb) {
    int i = blockIdx.x * 256 + threadIdx.x;      // 0 .. 81920
    if (i >= KP * HO) return;
    int j   = i & 7;
    int c15 = (i >> 3) & 15;
    int hi  = (i >> 7) & 3;
    int ctk = i >> 9;            // 0..159
    int ct  = ctk & 15;
    int ks  = ctk >> 4;
    int k = ks * 32 + hi * 8 + j;
    int c = ct * 16 + c15;
    float v = 0.f;
    if (k < F_IN) v = (c < HDIM) ? Wl[c * F_IN + k] : Wr[(c - HDIM) * F_IN + k];
    Wb[i] = f2bf(v);
}

// xPb[n][0:128] = bf16(x[n] @ Wl.T) ; xPb[n][128:256] = bf16(x[n] @ Wr.T)
__global__ __launch_bounds__(256) void proj_kernel(const float* __restrict__ x,
                                                   const unsigned short* __restrict__ Wb,
                                                   unsigned short* __restrict__ xPb, int N) {
    __shared__ unsigned short xs[NKS][4][MB][8];   // 40 KB, bank-even for ds_read_b128
    int tid = threadIdx.x;
    int n0 = blockIdx.x * MB;

    // ---- stage X tile (fp32 -> bf16), zero-pad rows>=N and k>=300 ----
    for (int i = tid; i < MB * 40; i += 256) {   // 10 iters: one 8-k group each
        int row = i / 40;
        int g   = i % 40;                        // k-group: ks=g>>2, hi=g&3
        int k0  = g * 8;
        int gr  = n0 + row;
        float vf[8];
#pragma unroll
        for (int j = 0; j < 8; ++j) vf[j] = 0.f;
        if (gr < N) {
            const float* xr = x + (size_t)gr * F_IN;
            if (k0 + 8 <= F_IN) {
                float4 v0 = *reinterpret_cast<const float4*>(xr + k0);
                float4 v1 = *reinterpret_cast<const float4*>(xr + k0 + 4);
                vf[0]=v0.x; vf[1]=v0.y; vf[2]=v0.z; vf[3]=v0.w;
                vf[4]=v1.x; vf[5]=v1.y; vf[6]=v1.z; vf[7]=v1.w;
            } else if (k0 < F_IN) {
#pragma unroll
                for (int j = 0; j < 8; ++j) if (k0 + j < F_IN) vf[j] = xr[k0 + j];
            }
        }
        unsigned short tmp[8];
#pragma unroll
        for (int j = 0; j < 8; ++j) tmp[j] = f2bf(vf[j]);
        *reinterpret_cast<short8*>(&xs[g >> 2][g & 3][row][0]) =
            *reinterpret_cast<const short8*>(tmp);
    }
    __syncthreads();

    // ---- MFMA K-loop: wave w owns rows n0+16w..n0+16w+15, all 256 cols ----
    int lane = tid & 63, w = tid >> 6;
    int lo = lane & 15, hi = lane >> 4;

    f32x4 acc[16];
#pragma unroll
    for (int ct = 0; ct < 16; ++ct) acc[ct] = (f32x4){0.f, 0.f, 0.f, 0.f};

#pragma unroll 2
    for (int ks = 0; ks < NKS; ++ks) {
        short8 a = *reinterpret_cast<const short8*>(&xs[ks][hi][w * 16 + lo][0]);
#pragma unroll
        for (int ct = 0; ct < 16; ++ct) {
            short8 b = *reinterpret_cast<const short8*>(
                Wb + (size_t)(ks * 16 + ct) * 512 + hi * 128 + lo * 8);
            acc[ct] = __builtin_amdgcn_mfma_f32_16x16x32_bf16(a, b, acc[ct], 0, 0, 0);
        }
    }

    // ---- epilogue: C row = hi*4+r, col = ct*16+lo ----
#pragma unroll
    for (int ct = 0; ct < 16; ++ct) {
#pragma unroll
        for (int r = 0; r < 4; ++r) {
            int row = n0 + w * 16 + hi * 4 + r;
            if (row < N) xPb[(size_t)row * HO + ct * 16 + lo] = f2bf(acc[ct][r]);
        }
    }
}

// ---- CSR build ----
__global__ __launch_bounds__(256) void count_kernel(const int* __restrict__ ei,
                                                    int* __restrict__ cnt, int E) {
    int e = blockIdx.x * 256 + threadIdx.x;
    if (e >= E) return;
    atomicAdd(&cnt[ei[E + e]], 1);   // dst
}

__global__ __launch_bounds__(256) void scan1_kernel(const int* __restrict__ cnt,
                                                    int* __restrict__ tmp,
                                                    int* __restrict__ bsum, int N) {
    __shared__ int ssum[256];
    int t = threadIdx.x;
    int base = blockIdx.x * CHUNK + t * 4;
    int c[4];
#pragma unroll
    for (int j = 0; j < 4; ++j) c[j] = (base + j < N) ? cnt[base + j] : 0;
    int s = c[0] + c[1] + c[2] + c[3];
    ssum[t] = s;
    __syncthreads();
    for (int off = 1; off < 256; off <<= 1) {
        int a = (t >= off) ? ssum[t - off] : 0;
        __syncthreads();
        ssum[t] += a;
        __syncthreads();
    }
    int run = ssum[t] - s;
#pragma unroll
    for (int j = 0; j < 4; ++j) {
        if (base + j < N) tmp[base + j] = run;
        run += c[j];
    }
    if (t == 255) bsum[blockIdx.x] = ssum[255];
}

__global__ __launch_bounds__(256) void scan2_kernel(int* __restrict__ bsum, int nb) {
    __shared__ int sd[256];
    int t = threadIdx.x;
    int v = (t < nb) ? bsum[t] : 0;
    sd[t] = v;
    __syncthreads();
    for (int off = 1; off < 256; off <<= 1) {
        int a = (t >= off) ? sd[t - off] : 0;
        __syncthreads();
        sd[t] += a;
        __syncthreads();
    }
    if (t < nb) bsum[t] = sd[t] - v;
}

__global__ __launch_bounds__(256) void scan3_kernel(const int* __restrict__ tmp,
                                                    const int* __restrict__ bsum,
                                                    int* __restrict__ rowptr,
                                                    int* __restrict__ cursor, int N) {
    int i = blockIdx.x * 256 + threadIdx.x;
    if (i >= N) return;
    int v = tmp[i] + bsum[i >> 10];
    rowptr[i] = v;
    cursor[i] = v;
}

__global__ __launch_bounds__(256) void fill_kernel(const int* __restrict__ ei,
                                                   int* __restrict__ cursor,
                                                   int* __restrict__ srcl, int E) {
    int e = blockIdx.x * 256 + threadIdx.x;
    if (e >= E) return;
    int s = ei[e];
    int d = ei[E + e];
    int pos = atomicAdd(&cursor[d], 1);
    srcl[pos] = s;
}

// gather mean + h = relu(mean + bl + xWr) + global_max_pool (batch sorted)
__global__ __launch_bounds__(128) void gather_pool_kernel(const unsigned short* __restrict__ xPb,
                                                          const int* __restrict__ rowptr,
                                                          const int* __restrict__ rowend,
                                                          const int* __restrict__ srcl,
                                                          const float* __restrict__ bl,
                                                          const int* __restrict__ batch,
                                                          float* __restrict__ gpool, int N) {
    int t = threadIdx.x;
    int n0 = blockIdx.x * NPB;
    if (n0 >= N) return;
    float blv = bl[t];
    float runmax = 0.f;
    int curg = batch[n0];
    int nmax = N - n0; if (nmax > NPB) nmax = NPB;
    for (int i = 0; i < nmax; ++i) {
        int n = n0 + i;
        int gb = batch[n];
        if (gb != curg) {
            atomicMax((unsigned int*)&gpool[curg * HDIM + t], __float_as_uint(runmax));
            runmax = 0.f;
            curg = gb;
        }
        int e0 = rowptr[n];
        int e1 = rowend[n];
        float acc = 0.f;
        for (int e = e0; e < e1; ++e) {
            int s = srcl[e];
            acc += bf2f(xPb[(size_t)s * HO + t]);
        }
        float rv = 1.0f / fmaxf((float)(e1 - e0), 1.0f);
        float h = fmaf(acc, rv, blv + bf2f(xPb[(size_t)n * HO + HDIM + t]));
        h = fmaxf(h, 0.f);
        runmax = fmaxf(runmax, h);
    }
    atomicMax((unsigned int*)&gpool[curg * HDIM + t], __float_as_uint(runmax));
}

__global__ __launch_bounds__(256) void root_kernel(const int* __restrict__ batch,
                                                   int* __restrict__ root, int N) {
    int i = blockIdx.x * 256 + threadIdx.x;
    if (i >= N) return;
    if (i == 0 || batch[i] != batch[i - 1]) root[batch[i]] = i;
}

__global__ __launch_bounds__(128) void final_kernel(const float* __restrict__ x,
                                                    const int* __restrict__ root,
                                                    const float* __restrict__ gpool,
                                                    const float* __restrict__ W0,
                                                    const float* __restrict__ b0,
                                                    const float* __restrict__ W1,
                                                    const float* __restrict__ b1,
                                                    const float* __restrict__ W2,
                                                    const float* __restrict__ b2,
                                                    float* __restrict__ out) {
    __shared__ float xrow[F_IN];
    __shared__ float cat[HO];
    __shared__ float h1s[HDIM];
    __shared__ float part[2][2];
    int g = blockIdx.x, t = threadIdx.x;
    int r = root[g];
    const float* xr = x + (size_t)r * F_IN;
    for (int k = t; k < F_IN; k += HDIM) xrow[k] = xr[k];
    __syncthreads();

    float a = b0[t];
    const float* w0r = W0 + t * F_IN;
    for (int k = 0; k < F_IN; ++k) a = fmaf(xrow[k], w0r[k], a);
    cat[t] = fmaxf(a, 0.f);
    cat[HDIM + t] = gpool[g * HDIM + t];
    __syncthreads();

    float s = b1[t];
    const float* w1r = W1 + t * HO;
    for (int k = 0; k < HO; ++k) s = fmaf(cat[k], w1r[k], s);
    h1s[t] = fmaxf(s, 0.f);
    __syncthreads();

    float hv = h1s[t];
    float p0 = hv * W2[t];
    float p1 = hv * W2[HDIM + t];
#pragma unroll
    for (int o2 = 32; o2 > 0; o2 >>= 1) {
        p0 += __shfl_down(p0, o2);
        p1 += __shfl_down(p1, o2);
    }
    int lane = t & 63, wv = t >> 6;
    if (lane == 0) { part[0][wv] = p0; part[1][wv] = p1; }
    __syncthreads();
    if (t == 0) {
        float z0 = part[0][0] + part[0][1] + b2[0];
        float z1 = part[1][0] + part[1][1] + b2[1];
        float m = fmaxf(z0, z1);
        float lse = m + logf(expf(z0 - m) + expf(z1 - m));
        out[g * CLS + 0] = z0 - lse;
        out[g * CLS + 1] = z1 - lse;
    }
}

extern "C" void kernel_launch(void* const* d_in, const int* in_sizes, int n_in,
                              void* d_out, int out_size, void* d_ws, size_t ws_size,
                              hipStream_t stream) {
    const float* x     = (const float*)d_in[0];
    const int*   ei    = (const int*)d_in[1];
    const int*   batch = (const int*)d_in[2];
    const float* Wl    = (const float*)d_in[3];
    const float* bl    = (const float*)d_in[4];
    const float* Wr    = (const float*)d_in[5];
    const float* W0    = (const float*)d_in[6];
    const float* b0    = (const float*)d_in[7];
    const float* W1    = (const float*)d_in[8];
    const float* b1    = (const float*)d_in[9];
    const float* W2    = (const float*)d_in[10];
    const float* b2    = (const float*)d_in[11];
    float* out = (float*)d_out;

    int N = in_sizes[2];
    int E = in_sizes[1] / 2;
    int G = out_size / CLS;

    char* ws = (char*)d_ws;
    size_t off = 0;
    auto carve = [&](size_t bytes) -> void* {
        void* p = ws + off;
        off += (bytes + 255) & ~(size_t)255;
        return p;
    };
    unsigned short* xPb = (unsigned short*)carve((size_t)N * HO * sizeof(unsigned short));
    char*  zbeg   = ws + off;
    int*   cnt    = (int*)carve((size_t)N * sizeof(int));
    float* gpool  = (float*)carve((size_t)G * HDIM * sizeof(float));
    char*  zend   = ws + off;
    int*   tmp    = (int*)carve((size_t)N * sizeof(int));
    int*   rowptr = (int*)carve((size_t)N * sizeof(int));
    int*   cursor = (int*)carve((size_t)N * sizeof(int));
    int*   srcl   = (int*)carve((size_t)E * sizeof(int));
    int*   bsum   = (int*)carve(1024 * sizeof(int));
    unsigned short* Wb = (unsigned short*)carve((size_t)KP * HO * sizeof(unsigned short));
    int*   root   = (int*)carve((size_t)G * sizeof(int));
    (void)ws_size; (void)n_in;

    int nb = (N + CHUNK - 1) / CHUNK;

    hipMemsetAsync(zbeg, 0, (size_t)(zend - zbeg), stream);

    prepw_kernel<<<(KP * HO + 255) / 256, 256, 0, stream>>>(Wl, Wr, Wb);
    proj_kernel<<<(N + MB - 1) / MB, 256, 0, stream>>>(x, Wb, xPb, N);

    count_kernel<<<(E + 255) / 256, 256, 0, stream>>>(ei, cnt, E);
    scan1_kernel<<<nb, 256, 0, stream>>>(cnt, tmp, bsum, N);
    scan2_kernel<<<1, 256, 0, stream>>>(bsum, nb);
    scan3_kernel<<<(N + 255) / 256, 256, 0, stream>>>(tmp, bsum, rowptr, cursor, N);
    fill_kernel<<<(E + 255) / 256, 256, 0, stream>>>(ei, cursor, srcl, E);

    gather_pool_kernel<<<(N + NPB - 1) / NPB, HDIM, 0, stream>>>(xPb, rowptr, cursor, srcl,
                                                                 bl, batch, gpool, N);
    root_kernel<<<(N + 255) / 256, 256, 0, stream>>>(batch, root, N);
    final_kernel<<<G, HDIM, 0, stream>>>(x, root, gpool, W0, b0, W1, b1, W2, b2, out);
}

// Round 4
// 212.590 us; speedup vs baseline: 4.2549x; 1.3739x over previous
//
#include <hip/hip_runtime.h>
#include <hip/hip_bf16.h>
#include <math.h>

#define F_IN 300
#define HDIM 128
#define HO   256   // combined Wl|Wr output dim
#define KP   320   // K padded to 10 x 32
#define NKS  10
#define CLS  2
#define MB   64    // node rows per proj tile
#define NPB  64    // nodes per gather/pool block
#define CHUNK 1024 // scan chunk (256 threads x 4)
#define PROJ_BLOCKS 512   // 2 blocks/CU x 256 CU

typedef short short8 __attribute__((ext_vector_type(8)));
typedef float f32x4 __attribute__((ext_vector_type(4)));

static __device__ __forceinline__ unsigned short f2bf(float f) {
    union { float f; unsigned int u; } v; v.f = f;
    unsigned int u = v.u;
    unsigned int r = (u + 0x7FFFu + ((u >> 16) & 1u)) >> 16;   // RNE
    return (unsigned short)r;
}
static __device__ __forceinline__ float bf2f(unsigned short h) {
    union { unsigned int u; float f; } v; v.u = ((unsigned int)h) << 16;
    return v.f;
}

// Pack W fragments: Wb[((ks*16+ct)*4+hi)*16+c15][j] bf16, k=ks*32+hi*8+j, c=ct*16+c15
__global__ __launch_bounds__(256) void prepw_kernel(const float* __restrict__ Wl,
                                                    const float* __restrict__ Wr,
                                                    unsigned short* __restrict__ Wb) {
    int i = blockIdx.x * 256 + threadIdx.x;
    if (i >= KP * HO) return;
    int j   = i & 7;
    int c15 = (i >> 3) & 15;
    int hi  = (i >> 7) & 3;
    int ctk = i >> 9;
    int ct  = ctk & 15;
    int ks  = ctk >> 4;
    int k = ks * 32 + hi * 8 + j;
    int c = ct * 16 + c15;
    float v = 0.f;
    if (k < F_IN) v = (c < HDIM) ? Wl[c * F_IN + k] : Wr[(c - HDIM) * F_IN + k];
    Wb[i] = f2bf(v);
}

// Persistent-B MFMA projection: each wave holds its 20 B-fragments in registers,
// blocks grid-stride over 64-row tiles of X staged in swizzled LDS.
__global__ __launch_bounds__(512, 4) void proj_kernel(const float* __restrict__ x,
                                                      const unsigned short* __restrict__ Wb,
                                                      unsigned short* __restrict__ xPb,
                                                      int N, int ntiles) {
    __shared__ unsigned short xs[MB * KP];   // 40 KB; byte layout g*1024 + ((row^(g&7))<<4)
    int tid = threadIdx.x;
    int lane = tid & 63, w = tid >> 6;       // wave 0..7 owns cols 32w..32w+31
    int lo = lane & 15, hi = lane >> 4;

    // ---- B prologue: 20 fragments resident in VGPRs ----
    short8 bfrag[NKS][2];
#pragma unroll
    for (int ks = 0; ks < NKS; ++ks)
#pragma unroll
        for (int c = 0; c < 2; ++c) {
            int ct = 2 * w + c;
            bfrag[ks][c] = *reinterpret_cast<const short8*>(
                Wb + (size_t)(ks * 16 + ct) * 512 + hi * 128 + lo * 8);
        }

    char* xsb = (char*)xs;

    for (int tile = blockIdx.x; tile < ntiles; tile += gridDim.x) {
        int n0 = tile * MB;

        // ---- stage X tile (fp32 -> bf16), swizzled LDS writes ----
#pragma unroll
        for (int it = 0; it < 5; ++it) {
            int idx = tid + it * 512;        // 0..2559
            int row = idx / 40;
            int g   = idx - row * 40;        // k-group 0..39, k0 = 8g
            int k0  = g * 8;
            int gr  = n0 + row;
            float vf[8];
#pragma unroll
            for (int j = 0; j < 8; ++j) vf[j] = 0.f;
            if (gr < N) {
                const float* xr = x + (size_t)gr * F_IN;
                if (k0 + 8 <= F_IN) {
                    float4 v0 = *reinterpret_cast<const float4*>(xr + k0);
                    float4 v1 = *reinterpret_cast<const float4*>(xr + k0 + 4);
                    vf[0]=v0.x; vf[1]=v0.y; vf[2]=v0.z; vf[3]=v0.w;
                    vf[4]=v1.x; vf[5]=v1.y; vf[6]=v1.z; vf[7]=v1.w;
                } else if (k0 < F_IN) {
#pragma unroll
                    for (int j = 0; j < 8; ++j) if (k0 + j < F_IN) vf[j] = xr[k0 + j];
                }
            }
            unsigned short tmp[8];
#pragma unroll
            for (int j = 0; j < 8; ++j) tmp[j] = f2bf(vf[j]);
            int boff = g * 1024 + ((row ^ (g & 7)) << 4);
            *reinterpret_cast<short8*>(xsb + boff) = *reinterpret_cast<const short8*>(tmp);
        }
        __syncthreads();

        // ---- MFMA: 40 ds_read_b128 + 80 MFMA per wave ----
        f32x4 acc[4][2];
#pragma unroll
        for (int r = 0; r < 4; ++r) {
            acc[r][0] = (f32x4){0.f, 0.f, 0.f, 0.f};
            acc[r][1] = (f32x4){0.f, 0.f, 0.f, 0.f};
        }
#pragma unroll
        for (int ks = 0; ks < NKS; ++ks) {
            int g = ks * 4 + hi;
            int lob = g * 1024 + ((lo ^ (g & 7)) << 4);
#pragma unroll
            for (int r = 0; r < 4; ++r) {
                short8 a = *reinterpret_cast<const short8*>(xsb + lob + r * 256);
                acc[r][0] = __builtin_amdgcn_mfma_f32_16x16x32_bf16(a, bfrag[ks][0], acc[r][0], 0, 0, 0);
                acc[r][1] = __builtin_amdgcn_mfma_f32_16x16x32_bf16(a, bfrag[ks][1], acc[r][1], 0, 0, 0);
            }
        }

        // ---- epilogue: C row = r*16 + hi*4 + rr, col = (2w+c)*16 + lo ----
#pragma unroll
        for (int r = 0; r < 4; ++r)
#pragma unroll
            for (int c = 0; c < 2; ++c)
#pragma unroll
                for (int rr = 0; rr < 4; ++rr) {
                    int row = n0 + r * 16 + hi * 4 + rr;
                    if (row < N)
                        xPb[(size_t)row * HO + (2 * w + c) * 16 + lo] = f2bf(acc[r][c][rr]);
                }
        __syncthreads();   // protect xs before next tile's staging
    }
}

// ---- CSR build ----
__global__ __launch_bounds__(256) void count_kernel(const int* __restrict__ ei,
                                                    int* __restrict__ cnt, int E) {
    int e = blockIdx.x * 256 + threadIdx.x;
    if (e >= E) return;
    atomicAdd(&cnt[ei[E + e]], 1);   // dst
}

__global__ __launch_bounds__(256) void scan1_kernel(const int* __restrict__ cnt,
                                                    int* __restrict__ tmp,
                                                    int* __restrict__ bsum, int N) {
    __shared__ int ssum[256];
    int t = threadIdx.x;
    int base = blockIdx.x * CHUNK + t * 4;
    int c[4];
#pragma unroll
    for (int j = 0; j < 4; ++j) c[j] = (base + j < N) ? cnt[base + j] : 0;
    int s = c[0] + c[1] + c[2] + c[3];
    ssum[t] = s;
    __syncthreads();
    for (int off = 1; off < 256; off <<= 1) {
        int a = (t >= off) ? ssum[t - off] : 0;
        __syncthreads();
        ssum[t] += a;
        __syncthreads();
    }
    int run = ssum[t] - s;
#pragma unroll
    for (int j = 0; j < 4; ++j) {
        if (base + j < N) tmp[base + j] = run;
        run += c[j];
    }
    if (t == 255) bsum[blockIdx.x] = ssum[255];
}

__global__ __launch_bounds__(256) void scan2_kernel(int* __restrict__ bsum, int nb) {
    __shared__ int sd[256];
    int t = threadIdx.x;
    int v = (t < nb) ? bsum[t] : 0;
    sd[t] = v;
    __syncthreads();
    for (int off = 1; off < 256; off <<= 1) {
        int a = (t >= off) ? sd[t - off] : 0;
        __syncthreads();
        sd[t] += a;
        __syncthreads();
    }
    if (t < nb) bsum[t] = sd[t] - v;
}

__global__ __launch_bounds__(256) void scan3_kernel(const int* __restrict__ tmp,
                                                    const int* __restrict__ bsum,
                                                    int* __restrict__ rowptr,
                                                    int* __restrict__ cursor, int N) {
    int i = blockIdx.x * 256 + threadIdx.x;
    if (i >= N) return;
    int v = tmp[i] + bsum[i >> 10];
    rowptr[i] = v;
    cursor[i] = v;
}

__global__ __launch_bounds__(256) void fill_kernel(const int* __restrict__ ei,
                                                   int* __restrict__ cursor,
                                                   int* __restrict__ srcl, int E) {
    int e = blockIdx.x * 256 + threadIdx.x;
    if (e >= E) return;
    int s = ei[e];
    int d = ei[E + e];
    int pos = atomicAdd(&cursor[d], 1);
    srcl[pos] = s;
}

// gather mean + h = relu(mean + bl + xWr) + global_max_pool (batch sorted)
__global__ __launch_bounds__(128) void gather_pool_kernel(const unsigned short* __restrict__ xPb,
                                                          const int* __restrict__ rowptr,
                                                          const int* __restrict__ rowend,
                                                          const int* __restrict__ srcl,
                                                          const float* __restrict__ bl,
                                                          const int* __restrict__ batch,
                                                          float* __restrict__ gpool, int N) {
    int t = threadIdx.x;
    int n0 = blockIdx.x * NPB;
    if (n0 >= N) return;
    float blv = bl[t];
    float runmax = 0.f;
    int curg = batch[n0];
    int nmax = N - n0; if (nmax > NPB) nmax = NPB;
    for (int i = 0; i < nmax; ++i) {
        int n = n0 + i;
        int gb = batch[n];
        if (gb != curg) {
            atomicMax((unsigned int*)&gpool[curg * HDIM + t], __float_as_uint(runmax));
            runmax = 0.f;
            curg = gb;
        }
        int e0 = rowptr[n];
        int e1 = rowend[n];
        float acc = 0.f;
        for (int e = e0; e < e1; ++e) {
            int s = srcl[e];
            acc += bf2f(xPb[(size_t)s * HO + t]);
        }
        float rv = 1.0f / fmaxf((float)(e1 - e0), 1.0f);
        float h = fmaf(acc, rv, blv + bf2f(xPb[(size_t)n * HO + HDIM + t]));
        h = fmaxf(h, 0.f);
        runmax = fmaxf(runmax, h);
    }
    atomicMax((unsigned int*)&gpool[curg * HDIM + t], __float_as_uint(runmax));
}

__global__ __launch_bounds__(256) void root_kernel(const int* __restrict__ batch,
                                                   int* __restrict__ root, int N) {
    int i = blockIdx.x * 256 + threadIdx.x;
    if (i >= N) return;
    if (i == 0 || batch[i] != batch[i - 1]) root[batch[i]] = i;
}

__global__ __launch_bounds__(128) void final_kernel(const float* __restrict__ x,
                                                    const int* __restrict__ root,
                                                    const float* __restrict__ gpool,
                                                    const float* __restrict__ W0,
                                                    const float* __restrict__ b0,
                                                    const float* __restrict__ W1,
                                                    const float* __restrict__ b1,
                                                    const float* __restrict__ W2,
                                                    const float* __restrict__ b2,
                                                    float* __restrict__ out) {
    __shared__ float xrow[F_IN];
    __shared__ float cat[HO];
    __shared__ float h1s[HDIM];
    __shared__ float part[2][2];
    int g = blockIdx.x, t = threadIdx.x;
    int r = root[g];
    const float* xr = x + (size_t)r * F_IN;
    for (int k = t; k < F_IN; k += HDIM) xrow[k] = xr[k];
    __syncthreads();

    float a = b0[t];
    const float* w0r = W0 + t * F_IN;
    for (int k = 0; k < F_IN; ++k) a = fmaf(xrow[k], w0r[k], a);
    cat[t] = fmaxf(a, 0.f);
    cat[HDIM + t] = gpool[g * HDIM + t];
    __syncthreads();

    float s = b1[t];
    const float* w1r = W1 + t * HO;
    for (int k = 0; k < HO; ++k) s = fmaf(cat[k], w1r[k], s);
    h1s[t] = fmaxf(s, 0.f);
    __syncthreads();

    float hv = h1s[t];
    float p0 = hv * W2[t];
    float p1 = hv * W2[HDIM + t];
#pragma unroll
    for (int o2 = 32; o2 > 0; o2 >>= 1) {
        p0 += __shfl_down(p0, o2);
        p1 += __shfl_down(p1, o2);
    }
    int lane = t & 63, wv = t >> 6;
    if (lane == 0) { part[0][wv] = p0; part[1][wv] = p1; }
    __syncthreads();
    if (t == 0) {
        float z0 = part[0][0] + part[0][1] + b2[0];
        float z1 = part[1][0] + part[1][1] + b2[1];
        float m = fmaxf(z0, z1);
        float lse = m + logf(expf(z0 - m) + expf(z1 - m));
        out[g * CLS + 0] = z0 - lse;
        out[g * CLS + 1] = z1 - lse;
    }
}

extern "C" void kernel_launch(void* const* d_in, const int* in_sizes, int n_in,
                              void* d_out, int out_size, void* d_ws, size_t ws_size,
                              hipStream_t stream) {
    const float* x     = (const float*)d_in[0];
    const int*   ei    = (const int*)d_in[1];
    const int*   batch = (const int*)d_in[2];
    const float* Wl    = (const float*)d_in[3];
    const float* bl    = (const float*)d_in[4];
    const float* Wr    = (const float*)d_in[5];
    const float* W0    = (const float*)d_in[6];
    const float* b0    = (const float*)d_in[7];
    const float* W1    = (const float*)d_in[8];
    const float* b1    = (const float*)d_in[9];
    const float* W2    = (const float*)d_in[10];
    const float* b2    = (const float*)d_in[11];
    float* out = (float*)d_out;

    int N = in_sizes[2];
    int E = in_sizes[1] / 2;
    int G = out_size / CLS;

    char* ws = (char*)d_ws;
    size_t off = 0;
    auto carve = [&](size_t bytes) -> void* {
        void* p = ws + off;
        off += (bytes + 255) & ~(size_t)255;
        return p;
    };
    unsigned short* xPb = (unsigned short*)carve((size_t)N * HO * sizeof(unsigned short));
    char*  zbeg   = ws + off;
    int*   cnt    = (int*)carve((size_t)N * sizeof(int));
    float* gpool  = (float*)carve((size_t)G * HDIM * sizeof(float));
    char*  zend   = ws + off;
    int*   tmp    = (int*)carve((size_t)N * sizeof(int));
    int*   rowptr = (int*)carve((size_t)N * sizeof(int));
    int*   cursor = (int*)carve((size_t)N * sizeof(int));
    int*   srcl   = (int*)carve((size_t)E * sizeof(int));
    int*   bsum   = (int*)carve(1024 * sizeof(int));
    unsigned short* Wb = (unsigned short*)carve((size_t)KP * HO * sizeof(unsigned short));
    int*   root   = (int*)carve((size_t)G * sizeof(int));
    (void)ws_size; (void)n_in;

    int nb = (N + CHUNK - 1) / CHUNK;
    int ntiles = (N + MB - 1) / MB;
    int pblocks = ntiles < PROJ_BLOCKS ? ntiles : PROJ_BLOCKS;

    hipMemsetAsync(zbeg, 0, (size_t)(zend - zbeg), stream);

    prepw_kernel<<<(KP * HO + 255) / 256, 256, 0, stream>>>(Wl, Wr, Wb);
    proj_kernel<<<pblocks, 512, 0, stream>>>(x, Wb, xPb, N, ntiles);

    count_kernel<<<(E + 255) / 256, 256, 0, stream>>>(ei, cnt, E);
    scan1_kernel<<<nb, 256, 0, stream>>>(cnt, tmp, bsum, N);
    scan2_kernel<<<1, 256, 0, stream>>>(bsum, nb);
    scan3_kernel<<<(N + 255) / 256, 256, 0, stream>>>(tmp, bsum, rowptr, cursor, N);
    fill_kernel<<<(E + 255) / 256, 256, 0, stream>>>(ei, cursor, srcl, E);

    gather_pool_kernel<<<(N + NPB - 1) / NPB, HDIM, 0, stream>>>(xPb, rowptr, cursor, srcl,
                                                                 bl, batch, gpool, N);
    root_kernel<<<(N + 255) / 256, 256, 0, stream>>>(batch, root, N);
    final_kernel<<<G, HDIM, 0, stream>>>(x, root, gpool, W0, b0, W1, b1, W2, b2, out);
}